// Round 10
// baseline (2153.661 us; speedup 1.0000x reference)
//
#include <hip/hip_runtime.h>

#define NN 100000
#define FIN 128
#define HD 32
#define EE 3200000
#define BKN 64              // nodes per bucket
#define NBUK 1563           // ceil(NN/64); max col 99999>>6 = 1562
#define EPB 6144            // edges per binning chunk
#define NBLK ((EE + EPB - 1) / EPB)   // 521

typedef unsigned int uint;
typedef unsigned short ushort;
typedef unsigned char uchar;
typedef float vfloat4 __attribute__((ext_vector_type(4)));

__device__ __forceinline__ ushort f2bf(float f) {
    uint b = __float_as_uint(f);
    return (ushort)((b + 0x7FFFu + ((b >> 16) & 1u)) >> 16);
}
__device__ __forceinline__ float bf2f(ushort u) {
    return __uint_as_float(((uint)u) << 16);
}

__device__ __forceinline__ int load_idx32(const int* __restrict__ ei, long long pos, int is64) {
    return is64 ? __builtin_nontemporal_load(ei + pos * 2)
                : __builtin_nontemporal_load(ei + pos);
}

// ---------------- passA: coarse histogram (64-node buckets) + dtype detect ----
__global__ __launch_bounds__(256) void passA_hist(const int* __restrict__ ei,
                                                  int* __restrict__ blockhist,
                                                  int* __restrict__ flag) {
    __shared__ int hist[NBUK];
    __shared__ int sis64;
    int tid = threadIdx.x, blk = blockIdx.x;
    for (int b = tid; b < NBUK; b += 256) hist[b] = 0;
    if (tid < 64) {
        uint v = 0;
#pragma unroll
        for (int r = 0; r < 4; r++) v |= ((const uint*)ei)[2 * (tid + 64 * r) + 1];
        unsigned long long nz = __ballot(v != 0u);
        if (tid == 0) sis64 = (nz == 0ULL) ? 1 : 0;
    }
    __syncthreads();
    int is64 = sis64;
    if (blk == 0 && tid == 0) *flag = is64;
    int e0 = blk * EPB, e1 = e0 + EPB; if (e1 > EE) e1 = EE;
    for (int e = e0 + tid; e < e1; e += 256) {
        int col = load_idx32(ei, (long long)EE + e, is64);
        atomicAdd(&hist[col >> 6], 1);
    }
    __syncthreads();
    for (int b = tid; b < NBUK; b += 256) blockhist[blk * NBUK + b] = hist[b];
}

// ---------------- per-bucket exclusive scan over chunks ----------------
__global__ void scan_bucket(const int* __restrict__ blockhist, int* __restrict__ off_local,
                            int* __restrict__ total) {
    int b = blockIdx.x;
    int l = threadIdx.x;         // 0..63
    int run = 0;
    for (int c = 0; c < NBLK; c += 64) {
        int blk = c + l;
        int v = (blk < NBLK) ? blockhist[blk * NBUK + b] : 0;
        int incl = v;
#pragma unroll
        for (int d = 1; d < 64; d <<= 1) {
            int t = __shfl_up(incl, d, 64);
            if (l >= d) incl += t;
        }
        if (blk < NBLK) off_local[blk * NBUK + b] = run + (incl - v);
        run += __shfl(incl, 63, 64);
    }
    if (l == 0) total[b] = run;
}

// single-wave running scan over NBUK buckets
__global__ void scan_total(const int* __restrict__ total, int* __restrict__ bstart) {
    int l = threadIdx.x;         // 0..63
    int run = 0;
    for (int c = 0; c < NBUK; c += 64) {
        int b = c + l;
        int v = (b < NBUK) ? total[b] : 0;
        int incl = v;
#pragma unroll
        for (int d = 1; d < 64; d <<= 1) {
            int t = __shfl_up(incl, d, 64);
            if (l >= d) incl += t;
        }
        if (b < NBUK) bstart[b] = run + (incl - v);
        run += __shfl(incl, 63, 64);
    }
    if (l == 0) bstart[NBUK] = run;
}

// ---------------- sortC: LDS-sorted chunk scatter into 64-node buckets --------
// rec = {row17 | bf15(wt)<<17, col32}
__global__ __launch_bounds__(512) void sortC_kernel(const int* __restrict__ ei,
                                                    const float* __restrict__ wt,
                                                    const int* __restrict__ bstart,
                                                    const int* __restrict__ off_local,
                                                    const int* __restrict__ blockhist,
                                                    uint2* __restrict__ erec2,
                                                    const int* __restrict__ flag) {
    __shared__ uint2 lrec[EPB];      // 49152 B
    __shared__ int lcombo[NBUK];     // 6252 B
    __shared__ int lcur[NBUK];       // 6252 B
    int tid = threadIdx.x, blk = blockIdx.x;
    if (tid < 64) {                  // wave 0: exclusive scan of this chunk's hist
        int run = 0;
        for (int c = 0; c < NBUK; c += 64) {
            int b = c + tid;
            int v = (b < NBUK) ? blockhist[blk * NBUK + b] : 0;
            int incl = v;
#pragma unroll
            for (int d = 1; d < 64; d <<= 1) {
                int t2 = __shfl_up(incl, d, 64);
                if (tid >= d) incl += t2;
            }
            if (b < NBUK) {
                int ls = run + incl - v;
                lcur[b] = ls;
                lcombo[b] = bstart[b] + off_local[blk * NBUK + b] - ls;
            }
            run += __shfl(incl, 63, 64);
        }
    }
    __syncthreads();
    int is64 = *flag;
    int e0 = blk * EPB, e1 = e0 + EPB; if (e1 > EE) e1 = EE;
    for (int e = e0 + tid; e < e1; e += 512) {
        int row = load_idx32(ei, e, is64);
        int col = load_idx32(ei, (long long)EE + e, is64);
        uint nb = __float_as_uint(__builtin_nontemporal_load(wt + e));
        uint enc = ((nb + 0x8000u) >> 16) & 0x7FFFu;
        int pos = atomicAdd(&lcur[col >> 6], 1);
        uint2 r; r.x = (uint)row | (enc << 17); r.y = (uint)col;
        lrec[pos] = r;
    }
    __syncthreads();
    int m = e1 - e0;
    for (int slot = tid; slot < m; slot += 512) {
        uint2 r = lrec[slot];
        int gpos = lcombo[r.y >> 6] + slot;
        erec2[gpos] = r;
    }
}

// ---------------- dinv: per-bucket weighted degree (light pass) ----------------
__global__ __launch_bounds__(256) void dinv_kernel(const uint2* __restrict__ erec2,
                                                   const int* __restrict__ bstart,
                                                   float* __restrict__ dinv) {
    __shared__ float wsum[BKN];
    int t = threadIdx.x, b = blockIdx.x;
    if (t < BKN) wsum[t] = 0.f;
    __syncthreads();
    int e0 = bstart[b], e1 = bstart[b + 1];
    for (int e = e0 + t; e < e1; e += 256) {
        uint2 r = erec2[e];
        atomicAdd(&wsum[r.y & 63], __uint_as_float((r.x >> 17) << 16));
    }
    __syncthreads();
    if (t < BKN) {
        int node = b * BKN + t;
        if (node < NN) dinv[node] = rsqrtf(1.0f + wsum[t]);   // 1 = self-loop
    }
}

// ---------------- xw = x @ [Wc_z | Wc_r | Wc_h]  (192B rows, dinv-folded) -----
// Feature j: zr-pair (z|r<<16) at byte 4j, h at byte 128+2j.
__global__ __launch_bounds__(256) void gemm_xw_kernel(
        const float* __restrict__ x,
        const float* __restrict__ Wz, const float* __restrict__ Wr, const float* __restrict__ Wh,
        const float* __restrict__ dinv,
        ushort* __restrict__ xw16) {
    __shared__ float Bs[128 * 96];
    __shared__ float AsT[8 * 128];
    int tid = threadIdx.x;
    int tx = tid & 31, ty = tid >> 5;
    int rowBase = blockIdx.x * 128;

    for (int e = tid; e < 4096; e += 256) { int k = e >> 5, c = e & 31; Bs[k * 96 + c]      = Wz[e]; }
    for (int e = tid; e < 4096; e += 256) { int k = e >> 5, c = e & 31; Bs[k * 96 + 32 + c] = Wr[e]; }
    for (int e = tid; e < 4096; e += 256) { int k = e >> 5, c = e & 31; Bs[k * 96 + 64 + c] = Wh[e]; }

    float acc0[16], acc1[16], acc2[16];
#pragma unroll
    for (int r = 0; r < 16; r++) { acc0[r] = 0.f; acc1[r] = 0.f; acc2[r] = 0.f; }

    int lr = tid >> 1;
    int lc = (tid & 1) * 4;
    for (int k0 = 0; k0 < 128; k0 += 8) {
        __syncthreads();
        int gr = rowBase + lr;
        vfloat4 a4 = (vfloat4)(0.f);
        if (gr < NN) a4 = __builtin_nontemporal_load((const vfloat4*)(x + (long long)gr * FIN + k0 + lc));
        AsT[(lc + 0) * 128 + lr] = a4.x;
        AsT[(lc + 1) * 128 + lr] = a4.y;
        AsT[(lc + 2) * 128 + lr] = a4.z;
        AsT[(lc + 3) * 128 + lr] = a4.w;
        __syncthreads();
#pragma unroll
        for (int kk = 0; kk < 8; kk++) {
            float b0 = Bs[(k0 + kk) * 96 + tx];
            float b1 = Bs[(k0 + kk) * 96 + 32 + tx];
            float b2 = Bs[(k0 + kk) * 96 + 64 + tx];
            const float4* ap = (const float4*)(AsT + kk * 128 + ty * 16);
            float4 a0 = ap[0], a1 = ap[1], a2 = ap[2], a3 = ap[3];
            float av[16] = {a0.x,a0.y,a0.z,a0.w, a1.x,a1.y,a1.z,a1.w,
                            a2.x,a2.y,a2.z,a2.w, a3.x,a3.y,a3.z,a3.w};
#pragma unroll
            for (int r = 0; r < 16; r++) {
                acc0[r] = fmaf(av[r], b0, acc0[r]);
                acc1[r] = fmaf(av[r], b1, acc1[r]);
                acc2[r] = fmaf(av[r], b2, acc2[r]);
            }
        }
    }
#pragma unroll
    for (int r = 0; r < 16; r++) {
        int gr = rowBase + ty * 16 + r;
        if (gr < NN) {
            float di = dinv[gr];
            ushort* o = xw16 + (long long)gr * 96;
            uint zr = (uint)f2bf(acc0[r] * di) | ((uint)f2bf(acc1[r] * di) << 16);
            *(uint*)(o + 2 * tx) = zr;
            o[64 + tx] = f2bf(acc2[r] * di);
        }
    }
}

// ---------------- aggACC: per-bucket LDS accumulation + gates + head ----------
// Block = bucket (64 nodes). Each 32-lane group takes an EQUAL 1/16 slice of
// the bucket's edge segment (perfect balance — no per-node degree convoy),
// gathers xw'[row] (4B zr + 2B h per lane), and atomically accumulates
// w*val into acc{Z,R,H}[col&63][j]. Bank pattern: lane j -> bank j; the two
// groups of a wave form free 2-way aliasing. One barrier, then gates read
// acc rows in place. Fine sort (old passB) eliminated: records read ONCE.
// LDS = 53,760 B -> 3 blocks/CU (24 waves). VGPR headroom to ~85 at 6 w/SIMD.
__global__ __launch_bounds__(512) void aggACC_kernel(
        const uint2* __restrict__ erec2, const int* __restrict__ bstart,
        const ushort* __restrict__ xw16, const float* __restrict__ dinv,
        const float* __restrict__ hprev,
        const float* __restrict__ bcz, const float* __restrict__ bcr, const float* __restrict__ bch,
        const float* __restrict__ Wlz, const float* __restrict__ blz,
        const float* __restrict__ Wlr, const float* __restrict__ blr,
        const float* __restrict__ Wlh, const float* __restrict__ blh,
        const float* __restrict__ Whead, const float* __restrict__ bhead,
        float* __restrict__ y, float* __restrict__ hnew) {
    __shared__ float accZ[BKN][32], accR[BKN][32], accH[BKN][32];   // 24576 B
    __shared__ float WzT[64 * 32], WrT[64 * 32], WhT[64 * 32];      // 24576 B
    __shared__ float rhs[16][32];                                   // 2048 B
    __shared__ uint  rwsh[16][32];                                  // 2048 B (also hp bits in epilogue)
    __shared__ uchar rcl[16][32];                                   // 512 B
    int tid = threadIdx.x, b = blockIdx.x;
    for (int e2 = tid; e2 < 2048; e2 += 512) {
        int jj = e2 >> 6, k = e2 & 63;
        WzT[k * 32 + jj] = Wlz[e2];
        WrT[k * 32 + jj] = Wlr[e2];
        WhT[k * 32 + jj] = Wlh[e2];
    }
    for (int q = tid; q < BKN * 32; q += 512) {
        ((float*)accZ)[q] = 0.f; ((float*)accR)[q] = 0.f; ((float*)accH)[q] = 0.f;
    }
    int s = tid >> 5, j = tid & 31;
    int e0 = bstart[b], e1 = bstart[b + 1];
    int L = ((e1 - e0) + 15) >> 4;
    int gb = e0 + s * L;
    int ge = gb + L; if (ge > e1) ge = e1;

    const char* xwb = (const char*)xw16;
    uint jo4 = 4u * (uint)j;
    uint jo2 = 128u + 2u * (uint)j;

    uint2 vcur = make_uint2(0u, 0u);
    if (gb + j < ge) vcur = erec2[gb + j];
    __syncthreads();   // zero + WT staging complete

#define REC(vv, aa, hh, cc)                                                \
    {                                                                      \
        float w_ = __uint_as_float(((vv) >> 17) << 16);                    \
        atomicAdd(&accZ[cc][j], w_ * __uint_as_float((aa) << 16));         \
        atomicAdd(&accR[cc][j], w_ * __uint_as_float((aa) & 0xFFFF0000u)); \
        atomicAdd(&accH[cc][j], w_ * bf2f(hh));                            \
    }

    for (int base = gb; base < ge; base += 32) {
        rwsh[s][j] = vcur.x;                   // group-local, half-wave: ordered
        rcl[s][j] = (uchar)(vcur.y & 63u);
        int en = base + 32 + j;
        uint2 vnext = make_uint2(0u, 0u);
        if (en < ge) vnext = erec2[en];
        int mm = ge - base; if (mm > 32) mm = 32;
        int t = 0;
        for (; t + 8 <= mm; t += 8) {
            uint v0 = rwsh[s][t + 0], v1 = rwsh[s][t + 1], v2 = rwsh[s][t + 2], v3 = rwsh[s][t + 3];
            uint v4 = rwsh[s][t + 4], v5 = rwsh[s][t + 5], v6 = rwsh[s][t + 6], v7 = rwsh[s][t + 7];
            int c0 = rcl[s][t + 0], c1 = rcl[s][t + 1], c2 = rcl[s][t + 2], c3 = rcl[s][t + 3];
            int c4 = rcl[s][t + 4], c5 = rcl[s][t + 5], c6 = rcl[s][t + 6], c7 = rcl[s][t + 7];
            uint b0 = (v0 & 0x1FFFFu) * 192u, b1 = (v1 & 0x1FFFFu) * 192u;
            uint b2 = (v2 & 0x1FFFFu) * 192u, b3 = (v3 & 0x1FFFFu) * 192u;
            uint b4 = (v4 & 0x1FFFFu) * 192u, b5 = (v5 & 0x1FFFFu) * 192u;
            uint b6 = (v6 & 0x1FFFFu) * 192u, b7 = (v7 & 0x1FFFFu) * 192u;
            uint a0 = *(const uint*)(xwb + b0 + jo4);
            uint a1 = *(const uint*)(xwb + b1 + jo4);
            uint a2 = *(const uint*)(xwb + b2 + jo4);
            uint a3 = *(const uint*)(xwb + b3 + jo4);
            uint a4 = *(const uint*)(xwb + b4 + jo4);
            uint a5 = *(const uint*)(xwb + b5 + jo4);
            uint a6 = *(const uint*)(xwb + b6 + jo4);
            uint a7 = *(const uint*)(xwb + b7 + jo4);
            ushort h0 = *(const ushort*)(xwb + b0 + jo2);
            ushort h1 = *(const ushort*)(xwb + b1 + jo2);
            ushort h2 = *(const ushort*)(xwb + b2 + jo2);
            ushort h3 = *(const ushort*)(xwb + b3 + jo2);
            ushort h4 = *(const ushort*)(xwb + b4 + jo2);
            ushort h5 = *(const ushort*)(xwb + b5 + jo2);
            ushort h6 = *(const ushort*)(xwb + b6 + jo2);
            ushort h7 = *(const ushort*)(xwb + b7 + jo2);
            REC(v0, a0, h0, c0) REC(v1, a1, h1, c1) REC(v2, a2, h2, c2) REC(v3, a3, h3, c3)
            REC(v4, a4, h4, c4) REC(v5, a5, h5, c5) REC(v6, a6, h6, c6) REC(v7, a7, h7, c7)
        }
        for (; t < mm; t++) {
            uint v0 = rwsh[s][t];
            int c0 = rcl[s][t];
            uint b0 = (v0 & 0x1FFFFu) * 192u;
            uint a0 = *(const uint*)(xwb + b0 + jo4);
            ushort h0 = *(const ushort*)(xwb + b0 + jo2);
            REC(v0, a0, h0, c0)
        }
        vcur = vnext;
    }
#undef REC

    __syncthreads();   // all accumulation complete (cross-group)

    // epilogue: group s handles nodes cl = s*4 .. s*4+3
#pragma unroll
    for (int q = 0; q < 4; q++) {
        int cl = s * 4 + q;
        int i = b * BKN + cl;
        if (i < NN) {
            float di = dinv[i];
            uint bi = (uint)i * 192u;
            uint zri = *(const uint*)(xwb + bi + jo4);
            float hself = bf2f(*(const ushort*)(xwb + bi + jo2));
            float cz = fmaf(di, accZ[cl][j] + __uint_as_float(zri << 16), bcz[j]);
            float cr = fmaf(di, accR[cl][j] + __uint_as_float(zri & 0xFFFF0000u), bcr[j]);
            float chv = fmaf(di, accH[cl][j] + hself, bch[j]);
            accZ[cl][j] = cz; accR[cl][j] = cr; accH[cl][j] = chv;  // in-place, group-local
            float hp = hprev[(long long)i * HD + j];
            rwsh[s][j] = __float_as_uint(hp);
            // group-local LDS, half-wave: no barrier needed
            float az = blz[j], arv = blr[j];
#pragma unroll
            for (int k = 0; k < 32; k++) {
                az  = fmaf(WzT[k * 32 + j], accZ[cl][k], az);
                arv = fmaf(WrT[k * 32 + j], accR[cl][k], arv);
            }
#pragma unroll
            for (int k = 0; k < 32; k++) {
                float v = __uint_as_float(rwsh[s][k]);
                az  = fmaf(WzT[(k + 32) * 32 + j], v, az);
                arv = fmaf(WrT[(k + 32) * 32 + j], v, arv);
            }
            float Z = 1.f / (1.f + __expf(-az));
            float R = 1.f / (1.f + __expf(-arv));
            rhs[s][j] = hp * R;
            float ah = blh[j];
#pragma unroll
            for (int k = 0; k < 32; k++) ah = fmaf(WhT[k * 32 + j], accH[cl][k], ah);
#pragma unroll
            for (int k = 0; k < 32; k++) ah = fmaf(WhT[(k + 32) * 32 + j], rhs[s][k], ah);
            float Ht = tanhf(ah);
            float hn = Z * hp + (1.f - Z) * Ht;
            float yv = fmaxf(hn, 0.f) * Whead[j];
#pragma unroll
            for (int m = 16; m; m >>= 1) yv += __shfl_xor(yv, m, 32);
            __builtin_nontemporal_store(hn, hnew + (long long)i * HD + j);
            if (j == 0) y[i] = yv + bhead[0];
        }
    }
}

extern "C" void kernel_launch(void* const* d_in, const int* in_sizes, int n_in,
                              void* d_out, int out_size, void* d_ws, size_t ws_size,
                              hipStream_t stream) {
    const float* x     = (const float*)d_in[0];
    const int*   ei    = (const int*)d_in[1];
    const float* wt    = (const float*)d_in[2];
    const float* hprev = (const float*)d_in[3];
    const float* Wcz = (const float*)d_in[4],  *bcz = (const float*)d_in[5];
    const float* Wlz = (const float*)d_in[6],  *blz = (const float*)d_in[7];
    const float* Wcr = (const float*)d_in[8],  *bcr = (const float*)d_in[9];
    const float* Wlr = (const float*)d_in[10], *blr = (const float*)d_in[11];
    const float* Wch = (const float*)d_in[12], *bch = (const float*)d_in[13];
    const float* Wlh = (const float*)d_in[14], *blh = (const float*)d_in[15];
    const float* Whead = (const float*)d_in[16], *bhead = (const float*)d_in[17];

    float* out_y = (float*)d_out;            // [N]
    float* out_h = (float*)d_out + NN;       // [N,32]

    // layout (float offsets): blockhist/off_local are NBLK*NBUK = 814,323 (pad 815,104)
    float* ws = (float*)d_ws;
    float* dinv      = ws;                                   // NN
    int*   bstart    = (int*)(ws + 100000);                  // NBUK+1 (pad 2048)
    int*   total     = (int*)(ws + 102048);                  // NBUK (pad 2048)
    int*   blockhist = (int*)(ws + 104096);                  // pad 815104
    int*   off_local = (int*)(ws + 919200);                  // pad 815104
    int*   flag      = (int*)(ws + 1734304);                 // pad 32
    uint2* erec2     = (uint2*)(ws + 1734336);               // EE uint2 (25.6 MB, 8B-aligned)
    ushort* xw16     = (ushort*)(ws + 1734336 + 2LL * EE);   // NN*96 ushorts (19.2 MB)

    passA_hist<<<NBLK, 256, 0, stream>>>(ei, blockhist, flag);
    scan_bucket<<<NBUK, 64, 0, stream>>>(blockhist, off_local, total);
    scan_total<<<1, 64, 0, stream>>>(total, bstart);
    sortC_kernel<<<NBLK, 512, 0, stream>>>(ei, wt, bstart, off_local, blockhist, erec2, flag);
    dinv_kernel<<<NBUK, 256, 0, stream>>>(erec2, bstart, dinv);
    gemm_xw_kernel<<<(NN + 127) / 128, 256, 0, stream>>>(x, Wcz, Wcr, Wch, dinv, xw16);
    aggACC_kernel<<<NBUK, 512, 0, stream>>>(
        erec2, bstart, xw16, dinv, hprev, bcz, bcr, bch,
        Wlz, blz, Wlr, blr, Wlh, blh, Whead, bhead, out_y, out_h);
}

// Round 11
// 429.916 us; speedup vs baseline: 5.0095x; 5.0095x over previous
//
#include <hip/hip_runtime.h>

#define NN 100000
#define FIN 128
#define HD 32
#define EE 3200000
#define NBUK 391            // coarse buckets of 256 nodes
#define EPB 6144            // edges per binning chunk (LDS-sort fits in 64KB)
#define NBLK ((EE + EPB - 1) / EPB)   // 521

typedef unsigned int uint;
typedef unsigned short ushort;
typedef float vfloat4 __attribute__((ext_vector_type(4)));   // clang vector: nontemporal-ok

__device__ __forceinline__ ushort f2bf(float f) {
    uint b = __float_as_uint(f);
    return (ushort)((b + 0x7FFFu + ((b >> 16) & 1u)) >> 16);
}
__device__ __forceinline__ float bf2f(ushort u) {
    return __uint_as_float(((uint)u) << 16);
}

// values < 2^31 and non-negative: for int64, low dword suffices
__device__ __forceinline__ int load_idx32(const int* __restrict__ ei, long long pos, int is64) {
    return is64 ? __builtin_nontemporal_load(ei + pos * 2)
                : __builtin_nontemporal_load(ei + pos);
}

// ---------------- passA: coarse histogram (LDS atomics only) + inline dtype detect ----------------
__global__ __launch_bounds__(256) void passA_hist(const int* __restrict__ ei,
                                                  int* __restrict__ blockhist,
                                                  int* __restrict__ flag) {
    __shared__ int hist[NBUK];
    __shared__ int sis64;
    int tid = threadIdx.x, blk = blockIdx.x;
    for (int b = tid; b < NBUK; b += 256) hist[b] = 0;
    if (tid < 64) {   // wave 0: detect int64 vs int32 (hi dwords of first 256 slots all zero => int64)
        uint v = 0;
#pragma unroll
        for (int r = 0; r < 4; r++) v |= ((const uint*)ei)[2 * (tid + 64 * r) + 1];
        unsigned long long nz = __ballot(v != 0u);
        if (tid == 0) sis64 = (nz == 0ULL) ? 1 : 0;
    }
    __syncthreads();
    int is64 = sis64;
    if (blk == 0 && tid == 0) *flag = is64;   // for sortC (runs after scan kernels)
    int e0 = blk * EPB, e1 = e0 + EPB; if (e1 > EE) e1 = EE;
    for (int e = e0 + tid; e < e1; e += 256) {
        int col = load_idx32(ei, (long long)EE + e, is64);
        atomicAdd(&hist[col >> 8], 1);
    }
    __syncthreads();
    for (int b = tid; b < NBUK; b += 256) blockhist[blk * NBUK + b] = hist[b];
}

// ---------------- per-bucket exclusive scan over chunks ----------------
__global__ void scan_bucket(const int* __restrict__ blockhist, int* __restrict__ off_local,
                            int* __restrict__ total) {
    int b = blockIdx.x;          // bucket
    int l = threadIdx.x;         // 0..63 (one wave)
    int run = 0;
    for (int c = 0; c < NBLK; c += 64) {
        int blk = c + l;
        int v = (blk < NBLK) ? blockhist[blk * NBUK + b] : 0;
        int incl = v;
#pragma unroll
        for (int d = 1; d < 64; d <<= 1) {
            int t = __shfl_up(incl, d, 64);
            if (l >= d) incl += t;
        }
        if (blk < NBLK) off_local[blk * NBUK + b] = run + (incl - v);
        run += __shfl(incl, 63, 64);
    }
    if (l == 0) total[b] = run;
}

__global__ void scan_total(const int* __restrict__ total, int* __restrict__ bstart) {
    __shared__ int sd[512];
    int t = threadIdx.x;
    int v = (t < NBUK) ? total[t] : 0;
    sd[t] = v;
    __syncthreads();
    for (int off = 1; off < 512; off <<= 1) {
        int x = (t >= off) ? sd[t - off] : 0;
        __syncthreads();
        sd[t] += x;
        __syncthreads();
    }
    if (t < NBUK) bstart[t] = sd[t] - v;
    if (t == NBUK - 1) bstart[NBUK] = sd[t];
}

// ---------------- sortC: LDS-sorted chunk scatter (coalesced writes) --------
// Records placed bucket-sorted in LDS, then streamed out contiguously.
// rec = {row17 | bf15(wt)<<17, col32}
__global__ __launch_bounds__(512) void sortC_kernel(const int* __restrict__ ei,
                                                    const float* __restrict__ wt,
                                                    const int* __restrict__ bstart,
                                                    const int* __restrict__ off_local,
                                                    const int* __restrict__ blockhist,
                                                    uint2* __restrict__ erec2,
                                                    const int* __restrict__ flag) {
    __shared__ uint2 lrec[EPB];      // 49152 B
    __shared__ int lcombo[NBUK];     // bstart[b] + off_local[blk][b] - lstart[b]
    __shared__ int lcur[NBUK];
    int tid = threadIdx.x, blk = blockIdx.x;
    if (tid < 64) {                  // wave 0: exclusive scan of this chunk's hist
        int run = 0;
        for (int c = 0; c < NBUK; c += 64) {
            int b = c + tid;
            int v = (b < NBUK) ? blockhist[blk * NBUK + b] : 0;
            int incl = v;
#pragma unroll
            for (int d = 1; d < 64; d <<= 1) {
                int t2 = __shfl_up(incl, d, 64);
                if (tid >= d) incl += t2;
            }
            if (b < NBUK) {
                int ls = run + incl - v;
                lcur[b] = ls;
                lcombo[b] = bstart[b] + off_local[blk * NBUK + b] - ls;
            }
            run += __shfl(incl, 63, 64);
        }
    }
    __syncthreads();
    int is64 = *flag;
    int e0 = blk * EPB, e1 = e0 + EPB; if (e1 > EE) e1 = EE;
    for (int e = e0 + tid; e < e1; e += 512) {
        int row = load_idx32(ei, e, is64);
        int col = load_idx32(ei, (long long)EE + e, is64);
        uint nb = __float_as_uint(__builtin_nontemporal_load(wt + e));
        uint enc = ((nb + 0x8000u) >> 16) & 0x7FFFu;   // bf16 round, drop sign(=0)
        int pos = atomicAdd(&lcur[col >> 8], 1);       // LDS atomic
        uint2 r; r.x = (uint)row | (enc << 17); r.y = (uint)col;
        lrec[pos] = r;
    }
    __syncthreads();
    int m = e1 - e0;
    for (int slot = tid; slot < m; slot += 512) {
        uint2 r = lrec[slot];
        int gpos = lcombo[r.y >> 8] + slot;
        erec2[gpos] = r;             // contiguous within each bucket segment
    }
}

// ---------------- passB: per-bucket fine sort + degree/dinv (fused) ----------
__global__ __launch_bounds__(512) void passB_fine(const uint2* __restrict__ erec2,
                                                  const int* __restrict__ bstart,
                                                  uint* __restrict__ erecF,
                                                  int* __restrict__ estart, int* __restrict__ cnt,
                                                  float* __restrict__ dinv) {
    __shared__ int hist[256];
    __shared__ float wsum[256];
    __shared__ int off[256];
    __shared__ int cur[256];
    __shared__ int sd[256];
    int t = threadIdx.x, b = blockIdx.x;
    if (t < 256) { hist[t] = 0; wsum[t] = 0.f; }
    __syncthreads();
    int e0 = bstart[b], e1 = bstart[b + 1];
    for (int e = e0 + t; e < e1; e += 512) {
        uint2 r = erec2[e];
        int cl = (int)(r.y & 255u);
        atomicAdd(&hist[cl], 1);
        atomicAdd(&wsum[cl], __uint_as_float((r.x >> 17) << 16));
    }
    __syncthreads();
    int v = 0;
    if (t < 256) { v = hist[t]; sd[t] = v; }
    __syncthreads();
    for (int o = 1; o < 256; o <<= 1) {
        int x = (t >= o && t < 256) ? sd[t - o] : 0;
        __syncthreads();
        if (t < 256) sd[t] += x;
        __syncthreads();
    }
    if (t < 256) {
        off[t] = sd[t] - v;
        cur[t] = 0;
        int node = b * 256 + t;
        if (node < NN) {
            estart[node] = e0 + off[t];
            cnt[node] = v;
            dinv[node] = rsqrtf(1.0f + wsum[t]);   // 1 = self-loop weight
        }
    }
    __syncthreads();
    for (int e = e0 + t; e < e1; e += 512) {
        uint2 r = erec2[e];
        int cl = (int)(r.y & 255u);
        int p = atomicAdd(&cur[cl], 1);        // LDS atomic
        erecF[e0 + off[cl] + p] = r.x;         // dense per-node-sorted (hot 32KB window)
    }
}

// ---------------- xw = x @ [Wc_z | Wc_r | Wc_h]  (192B rows, dinv-folded) -----
// Feature j: zr-pair (z_j | r_j<<16) at byte 4j;  h_j at byte 128 + 2j.
// dinv[row] folded here. xw16 ALIASES erec2 (dead after passB; same stream).
__global__ __launch_bounds__(256) void gemm_xw_kernel(
        const float* __restrict__ x,
        const float* __restrict__ Wz, const float* __restrict__ Wr, const float* __restrict__ Wh,
        const float* __restrict__ dinv,
        ushort* __restrict__ xw16) {
    __shared__ float Bs[128 * 96];   // Bs[k*96 + c], k GLOBAL (0..127)
    __shared__ float AsT[8 * 128];   // AsT[kk*128 + row], kk local (0..7)
    int tid = threadIdx.x;
    int tx = tid & 31, ty = tid >> 5;
    int rowBase = blockIdx.x * 128;

    for (int e = tid; e < 4096; e += 256) { int k = e >> 5, c = e & 31; Bs[k * 96 + c]      = Wz[e]; }
    for (int e = tid; e < 4096; e += 256) { int k = e >> 5, c = e & 31; Bs[k * 96 + 32 + c] = Wr[e]; }
    for (int e = tid; e < 4096; e += 256) { int k = e >> 5, c = e & 31; Bs[k * 96 + 64 + c] = Wh[e]; }

    float acc0[16], acc1[16], acc2[16];
#pragma unroll
    for (int r = 0; r < 16; r++) { acc0[r] = 0.f; acc1[r] = 0.f; acc2[r] = 0.f; }

    int lr = tid >> 1;
    int lc = (tid & 1) * 4;
    for (int k0 = 0; k0 < 128; k0 += 8) {
        __syncthreads();
        int gr = rowBase + lr;
        vfloat4 a4 = (vfloat4)(0.f);
        if (gr < NN) a4 = __builtin_nontemporal_load((const vfloat4*)(x + (long long)gr * FIN + k0 + lc));
        AsT[(lc + 0) * 128 + lr] = a4.x;
        AsT[(lc + 1) * 128 + lr] = a4.y;
        AsT[(lc + 2) * 128 + lr] = a4.z;
        AsT[(lc + 3) * 128 + lr] = a4.w;
        __syncthreads();
#pragma unroll
        for (int kk = 0; kk < 8; kk++) {
            float b0 = Bs[(k0 + kk) * 96 + tx];
            float b1 = Bs[(k0 + kk) * 96 + 32 + tx];
            float b2 = Bs[(k0 + kk) * 96 + 64 + tx];
            const float4* ap = (const float4*)(AsT + kk * 128 + ty * 16);
            float4 a0 = ap[0], a1 = ap[1], a2 = ap[2], a3 = ap[3];
            float av[16] = {a0.x,a0.y,a0.z,a0.w, a1.x,a1.y,a1.z,a1.w,
                            a2.x,a2.y,a2.z,a2.w, a3.x,a3.y,a3.z,a3.w};
#pragma unroll
            for (int r = 0; r < 16; r++) {
                acc0[r] = fmaf(av[r], b0, acc0[r]);
                acc1[r] = fmaf(av[r], b1, acc1[r]);
                acc2[r] = fmaf(av[r], b2, acc2[r]);
            }
        }
    }
#pragma unroll
    for (int r = 0; r < 16; r++) {
        int gr = rowBase + ty * 16 + r;
        if (gr < NN) {
            float di = dinv[gr];
            ushort* o = xw16 + (long long)gr * 96;    // 192B row
            uint zr = (uint)f2bf(acc0[r] * di) | ((uint)f2bf(acc1[r] * di) << 16);
            *(uint*)(o + 2 * tx) = zr;                // 4B coalesced
            o[64 + tx] = f2bf(acc2[r] * di);          // 2B
        }
    }
}

// ---------------- fused gather-aggregate + GRU gates + head ----------------
// 32-lane group per node; 16 nodes / 512-thread block; NN = 6250*16 exactly.
// xw16 rows pre-scaled by dinv[row]:  agg = dinv[col]*(sum w_e*xw'[row_e] + xw'[col])
// 192B rows, two loads/edge (4B zr + 2B h).
// BARRIERS KEPT (register-pressure fences): removing them -> VGPR 80,
// occupancy 22% (rounds 3/4). Unroll-8 first tier (round 6: +3%).
// WT staging indexed so consecutive lanes write consecutive banks
// (jj = e&31): the old (k = e&63) form put all 64 lanes in bank 0.
// Rounds 8/10 established: direct-scatter and LDS-accumulate variants lose
// by integer factors — this sorted-record + register-accum shape is right.
__global__ __launch_bounds__(512) void agg_gate_kernel(
        const uint* __restrict__ erecF, const int* __restrict__ estart, const int* __restrict__ cnt,
        const ushort* __restrict__ xw16, const float* __restrict__ dinv,
        const float* __restrict__ hprev,
        const float* __restrict__ bcz, const float* __restrict__ bcr, const float* __restrict__ bch,
        const float* __restrict__ Wlz, const float* __restrict__ blz,
        const float* __restrict__ Wlr, const float* __restrict__ blr,
        const float* __restrict__ Wlh, const float* __restrict__ blh,
        const float* __restrict__ Whead, const float* __restrict__ bhead,
        float* __restrict__ y, float* __restrict__ hnew) {
    __shared__ float WzT[64 * 32], WrT[64 * 32], WhT[64 * 32];  // WT[k*32+j] = Wl[j*64+k]
    __shared__ float czs[16][32], crs[16][32], chs[16][32], hps[16][32], rhs[16][32];
    __shared__ uint rwsh[16][32];   // staged records per group
    int tid = threadIdx.x;
    for (int e2 = tid; e2 < 2048; e2 += 512) {
        int jj = e2 & 31, k = e2 >> 5;           // lane-consecutive jj: bank-conflict-free writes
        WzT[k * 32 + jj] = Wlz[jj * 64 + k];     // strided global reads: L2-hot (reused x6250 blocks)
        WrT[k * 32 + jj] = Wlr[jj * 64 + k];
        WhT[k * 32 + jj] = Wlh[jj * 64 + k];
    }
    int s = tid >> 5, j = tid & 31;
    int i = blockIdx.x * 16 + s;
    int beg = estart[i], c = cnt[i], end = beg + c;

    const char* xwb = (const char*)xw16;
    uint jo4 = 4u * (uint)j;            // byte offset of feature j's zr pair
    uint jo2 = 128u + 2u * (uint)j;     // byte offset of feature j's h

    float cz = 0.f, cr = 0.f, ch = 0.f;
    int e = beg + j;
    uint vcur = (e < end) ? __builtin_nontemporal_load(erecF + e) : 0u;   // batch 0
    __syncthreads();   // WT staging complete

#define REC(vv, aa, hh)                                                    \
    {                                                                      \
        float w_ = __uint_as_float(((vv) >> 17) << 16);                    \
        cz = fmaf(w_, __uint_as_float((aa) << 16), cz);                    \
        cr = fmaf(w_, __uint_as_float((aa) & 0xFFFF0000u), cr);            \
        ch = fmaf(w_, bf2f(hh), ch);                                       \
    }

    for (int base = beg; base < end; base += 32) {
        rwsh[s][j] = vcur;                      // in-order DS within wave: safe
        int en = base + 32 + j;
        uint vnext = (en < end) ? __builtin_nontemporal_load(erecF + en) : 0u;  // prefetch next batch
        int mm = end - base; if (mm > 32) mm = 32;
        int t = 0;
        for (; t + 8 <= mm; t += 8) {           // 16 loads in flight per group
            uint v0 = rwsh[s][t + 0], v1 = rwsh[s][t + 1], v2 = rwsh[s][t + 2], v3 = rwsh[s][t + 3];
            uint v4 = rwsh[s][t + 4], v5 = rwsh[s][t + 5], v6 = rwsh[s][t + 6], v7 = rwsh[s][t + 7];
            uint b0 = (v0 & 0x1FFFFu) * 192u, b1 = (v1 & 0x1FFFFu) * 192u;
            uint b2 = (v2 & 0x1FFFFu) * 192u, b3 = (v3 & 0x1FFFFu) * 192u;
            uint b4 = (v4 & 0x1FFFFu) * 192u, b5 = (v5 & 0x1FFFFu) * 192u;
            uint b6 = (v6 & 0x1FFFFu) * 192u, b7 = (v7 & 0x1FFFFu) * 192u;
            uint a0 = *(const uint*)(xwb + b0 + jo4);
            uint a1 = *(const uint*)(xwb + b1 + jo4);
            uint a2 = *(const uint*)(xwb + b2 + jo4);
            uint a3 = *(const uint*)(xwb + b3 + jo4);
            uint a4 = *(const uint*)(xwb + b4 + jo4);
            uint a5 = *(const uint*)(xwb + b5 + jo4);
            uint a6 = *(const uint*)(xwb + b6 + jo4);
            uint a7 = *(const uint*)(xwb + b7 + jo4);
            ushort h0 = *(const ushort*)(xwb + b0 + jo2);
            ushort h1 = *(const ushort*)(xwb + b1 + jo2);
            ushort h2 = *(const ushort*)(xwb + b2 + jo2);
            ushort h3 = *(const ushort*)(xwb + b3 + jo2);
            ushort h4 = *(const ushort*)(xwb + b4 + jo2);
            ushort h5 = *(const ushort*)(xwb + b5 + jo2);
            ushort h6 = *(const ushort*)(xwb + b6 + jo2);
            ushort h7 = *(const ushort*)(xwb + b7 + jo2);
            REC(v0, a0, h0) REC(v1, a1, h1) REC(v2, a2, h2) REC(v3, a3, h3)
            REC(v4, a4, h4) REC(v5, a5, h5) REC(v6, a6, h6) REC(v7, a7, h7)
        }
        for (; t + 4 <= mm; t += 4) {
            uint v0 = rwsh[s][t + 0], v1 = rwsh[s][t + 1], v2 = rwsh[s][t + 2], v3 = rwsh[s][t + 3];
            uint b0 = (v0 & 0x1FFFFu) * 192u, b1 = (v1 & 0x1FFFFu) * 192u;
            uint b2 = (v2 & 0x1FFFFu) * 192u, b3 = (v3 & 0x1FFFFu) * 192u;
            uint a0 = *(const uint*)(xwb + b0 + jo4);
            uint a1 = *(const uint*)(xwb + b1 + jo4);
            uint a2 = *(const uint*)(xwb + b2 + jo4);
            uint a3 = *(const uint*)(xwb + b3 + jo4);
            ushort h0 = *(const ushort*)(xwb + b0 + jo2);
            ushort h1 = *(const ushort*)(xwb + b1 + jo2);
            ushort h2 = *(const ushort*)(xwb + b2 + jo2);
            ushort h3 = *(const ushort*)(xwb + b3 + jo2);
            REC(v0, a0, h0) REC(v1, a1, h1) REC(v2, a2, h2) REC(v3, a3, h3)
        }
        for (; t < mm; t++) {
            uint v0 = rwsh[s][t];
            uint b0 = (v0 & 0x1FFFFu) * 192u;
            uint a0 = *(const uint*)(xwb + b0 + jo4);
            ushort h0 = *(const ushort*)(xwb + b0 + jo2);
            REC(v0, a0, h0)
        }
        vcur = vnext;
    }
#undef REC

    // self-loop + dinv[col] + bias:  c* = di*(sum + xw'[i]) + bc
    float di = dinv[i];
    uint bi = (uint)i * 192u;
    uint zri = *(const uint*)(xwb + bi + jo4);
    float hself = bf2f(*(const ushort*)(xwb + bi + jo2));
    czs[s][j] = fmaf(di, cz + __uint_as_float(zri << 16), bcz[j]);
    crs[s][j] = fmaf(di, cr + __uint_as_float(zri & 0xFFFF0000u), bcr[j]);
    chs[s][j] = fmaf(di, ch + hself, bch[j]);
    float hp = hprev[(long long)i * HD + j];
    hps[s][j] = hp;
    __syncthreads();   // register-pressure fence + cross-group visibility

    float az = blz[j], arv = blr[j];
#pragma unroll
    for (int k = 0; k < 32; k++) {
        az  = fmaf(WzT[k * 32 + j], czs[s][k], az);
        arv = fmaf(WrT[k * 32 + j], crs[s][k], arv);
    }
#pragma unroll
    for (int k = 0; k < 32; k++) {
        float v = hps[s][k];
        az  = fmaf(WzT[(k + 32) * 32 + j], v, az);
        arv = fmaf(WrT[(k + 32) * 32 + j], v, arv);
    }
    float Z = 1.f / (1.f + __expf(-az));
    float R = 1.f / (1.f + __expf(-arv));
    rhs[s][j] = hp * R;
    __syncthreads();   // register-pressure fence

    float ah = blh[j];
#pragma unroll
    for (int k = 0; k < 32; k++) ah = fmaf(WhT[k * 32 + j], chs[s][k], ah);
#pragma unroll
    for (int k = 0; k < 32; k++) ah = fmaf(WhT[(k + 32) * 32 + j], rhs[s][k], ah);
    float Ht = tanhf(ah);
    float hn = Z * hp + (1.f - Z) * Ht;
    float yv = fmaxf(hn, 0.f) * Whead[j];
#pragma unroll
    for (int m = 16; m; m >>= 1) yv += __shfl_xor(yv, m, 32);
    __builtin_nontemporal_store(hn, hnew + (long long)i * HD + j);
    if (j == 0) y[i] = yv + bhead[0];
}

extern "C" void kernel_launch(void* const* d_in, const int* in_sizes, int n_in,
                              void* d_out, int out_size, void* d_ws, size_t ws_size,
                              hipStream_t stream) {
    const float* x     = (const float*)d_in[0];
    const int*   ei    = (const int*)d_in[1];
    const float* wt    = (const float*)d_in[2];
    const float* hprev = (const float*)d_in[3];
    const float* Wcz = (const float*)d_in[4],  *bcz = (const float*)d_in[5];
    const float* Wlz = (const float*)d_in[6],  *blz = (const float*)d_in[7];
    const float* Wcr = (const float*)d_in[8],  *bcr = (const float*)d_in[9];
    const float* Wlr = (const float*)d_in[10], *blr = (const float*)d_in[11];
    const float* Wch = (const float*)d_in[12], *bch = (const float*)d_in[13];
    const float* Wlh = (const float*)d_in[14], *blh = (const float*)d_in[15];
    const float* Whead = (const float*)d_in[16], *bhead = (const float*)d_in[17];

    float* out_y = (float*)d_out;            // [N]
    float* out_h = (float*)d_out + NN;       // [N,32]

    float* ws = (float*)d_ws;
    float* dinv      = ws;                                   // NN f32
    int*   estart    = (int*)(ws + NN);                      // NN
    int*   cnt       = (int*)(ws + 2LL * NN);                // NN
    int*   bstart    = (int*)(ws + 3LL * NN);                // NBUK+1 (pad 512)
    int*   total     = (int*)(ws + 3LL * NN + 512);          // NBUK (pad 512)
    int*   blockhist = (int*)(ws + 3LL * NN + 1024);         // NBLK*NBUK=203711 (pad 204000)
    int*   off_local = (int*)(ws + 3LL * NN + 205024);       // 203711 (pad 204000)
    int*   flag      = (int*)(ws + 3LL * NN + 409024);       // 1 (pad 32)
    uint2*  erec2    = (uint2*)(ws + 3LL * NN + 409056);     // EE uint2 (8B-aligned)
    ushort* xw16     = (ushort*)erec2;                       // ALIAS: NN*192B (19.2MB) <= EE*8B (25.6MB)
    uint*   erecF    = (uint*)(ws + 3LL * NN + 409056 + 2LL * EE);  // EE uint

    passA_hist<<<NBLK, 256, 0, stream>>>(ei, blockhist, flag);
    scan_bucket<<<NBUK, 64, 0, stream>>>(blockhist, off_local, total);
    scan_total<<<1, 512, 0, stream>>>(total, bstart);
    sortC_kernel<<<NBLK, 512, 0, stream>>>(ei, wt, bstart, off_local, blockhist, erec2, flag);
    passB_fine<<<NBUK, 512, 0, stream>>>(erec2, bstart, erecF, estart, cnt, dinv);
    gemm_xw_kernel<<<(NN + 127) / 128, 256, 0, stream>>>(x, Wcz, Wcr, Wch, dinv, xw16);
    agg_gate_kernel<<<NN / 16, 512, 0, stream>>>(
        erecF, estart, cnt, xw16, dinv, hprev, bcz, bcr, bch,
        Wlz, blz, Wlr, blr, Wlh, blh, Whead, bhead, out_y, out_h);
}

// Round 12
// 415.152 us; speedup vs baseline: 5.1876x; 1.0356x over previous
//
#include <hip/hip_runtime.h>

#define NN 100000
#define FIN 128
#define HD 32
#define EE 3200000
#define NBUK 391            // coarse buckets of 256 nodes
#define EPB 6144            // edges per binning chunk (LDS-sort fits in 64KB)
#define NBLK ((EE + EPB - 1) / EPB)   // 521

typedef unsigned int uint;
typedef unsigned short ushort;
typedef float vfloat4 __attribute__((ext_vector_type(4)));   // clang vector: nontemporal-ok

__device__ __forceinline__ ushort f2bf(float f) {
    uint b = __float_as_uint(f);
    return (ushort)((b + 0x7FFFu + ((b >> 16) & 1u)) >> 16);
}
__device__ __forceinline__ float bf2f(ushort u) {
    return __uint_as_float(((uint)u) << 16);
}

// values < 2^31 and non-negative: for int64, low dword suffices
__device__ __forceinline__ int load_idx32(const int* __restrict__ ei, long long pos, int is64) {
    return is64 ? __builtin_nontemporal_load(ei + pos * 2)
                : __builtin_nontemporal_load(ei + pos);
}

// ---------------- passA: coarse histogram (LDS atomics only) + inline dtype detect ----------------
__global__ __launch_bounds__(256) void passA_hist(const int* __restrict__ ei,
                                                  int* __restrict__ blockhist,
                                                  int* __restrict__ flag) {
    __shared__ int hist[NBUK];
    __shared__ int sis64;
    int tid = threadIdx.x, blk = blockIdx.x;
    for (int b = tid; b < NBUK; b += 256) hist[b] = 0;
    if (tid < 64) {   // wave 0: detect int64 vs int32 (hi dwords of first 256 slots all zero => int64)
        uint v = 0;
#pragma unroll
        for (int r = 0; r < 4; r++) v |= ((const uint*)ei)[2 * (tid + 64 * r) + 1];
        unsigned long long nz = __ballot(v != 0u);
        if (tid == 0) sis64 = (nz == 0ULL) ? 1 : 0;
    }
    __syncthreads();
    int is64 = sis64;
    if (blk == 0 && tid == 0) *flag = is64;   // for sortC (runs after scan kernels)
    int e0 = blk * EPB, e1 = e0 + EPB; if (e1 > EE) e1 = EE;
    for (int e = e0 + tid; e < e1; e += 256) {
        int col = load_idx32(ei, (long long)EE + e, is64);
        atomicAdd(&hist[col >> 8], 1);
    }
    __syncthreads();
    for (int b = tid; b < NBUK; b += 256) blockhist[blk * NBUK + b] = hist[b];
}

// ---------------- per-bucket exclusive scan over chunks ----------------
__global__ void scan_bucket(const int* __restrict__ blockhist, int* __restrict__ off_local,
                            int* __restrict__ total) {
    int b = blockIdx.x;          // bucket
    int l = threadIdx.x;         // 0..63 (one wave)
    int run = 0;
    for (int c = 0; c < NBLK; c += 64) {
        int blk = c + l;
        int v = (blk < NBLK) ? blockhist[blk * NBUK + b] : 0;
        int incl = v;
#pragma unroll
        for (int d = 1; d < 64; d <<= 1) {
            int t = __shfl_up(incl, d, 64);
            if (l >= d) incl += t;
        }
        if (blk < NBLK) off_local[blk * NBUK + b] = run + (incl - v);
        run += __shfl(incl, 63, 64);
    }
    if (l == 0) total[b] = run;
}

__global__ void scan_total(const int* __restrict__ total, int* __restrict__ bstart) {
    __shared__ int sd[512];
    int t = threadIdx.x;
    int v = (t < NBUK) ? total[t] : 0;
    sd[t] = v;
    __syncthreads();
    for (int off = 1; off < 512; off <<= 1) {
        int x = (t >= off) ? sd[t - off] : 0;
        __syncthreads();
        sd[t] += x;
        __syncthreads();
    }
    if (t < NBUK) bstart[t] = sd[t] - v;
    if (t == NBUK - 1) bstart[NBUK] = sd[t];
}

// ---------------- sortC: LDS-sorted chunk scatter (coalesced writes) --------
// Records placed bucket-sorted in LDS, then streamed out contiguously.
// rec = {row17 | bf15(wt)<<17, col32}
__global__ __launch_bounds__(512) void sortC_kernel(const int* __restrict__ ei,
                                                    const float* __restrict__ wt,
                                                    const int* __restrict__ bstart,
                                                    const int* __restrict__ off_local,
                                                    const int* __restrict__ blockhist,
                                                    uint2* __restrict__ erec2,
                                                    const int* __restrict__ flag) {
    __shared__ uint2 lrec[EPB];      // 49152 B
    __shared__ int lcombo[NBUK];     // bstart[b] + off_local[blk][b] - lstart[b]
    __shared__ int lcur[NBUK];
    int tid = threadIdx.x, blk = blockIdx.x;
    if (tid < 64) {                  // wave 0: exclusive scan of this chunk's hist
        int run = 0;
        for (int c = 0; c < NBUK; c += 64) {
            int b = c + tid;
            int v = (b < NBUK) ? blockhist[blk * NBUK + b] : 0;
            int incl = v;
#pragma unroll
            for (int d = 1; d < 64; d <<= 1) {
                int t2 = __shfl_up(incl, d, 64);
                if (tid >= d) incl += t2;
            }
            if (b < NBUK) {
                int ls = run + incl - v;
                lcur[b] = ls;
                lcombo[b] = bstart[b] + off_local[blk * NBUK + b] - ls;
            }
            run += __shfl(incl, 63, 64);
        }
    }
    __syncthreads();
    int is64 = *flag;
    int e0 = blk * EPB, e1 = e0 + EPB; if (e1 > EE) e1 = EE;
    for (int e = e0 + tid; e < e1; e += 512) {
        int row = load_idx32(ei, e, is64);
        int col = load_idx32(ei, (long long)EE + e, is64);
        uint nb = __float_as_uint(__builtin_nontemporal_load(wt + e));
        uint enc = ((nb + 0x8000u) >> 16) & 0x7FFFu;   // bf16 round, drop sign(=0)
        int pos = atomicAdd(&lcur[col >> 8], 1);       // LDS atomic
        uint2 r; r.x = (uint)row | (enc << 17); r.y = (uint)col;
        lrec[pos] = r;
    }
    __syncthreads();
    int m = e1 - e0;
    for (int slot = tid; slot < m; slot += 512) {
        uint2 r = lrec[slot];
        int gpos = lcombo[r.y >> 8] + slot;
        erec2[gpos] = r;             // contiguous within each bucket segment
    }
}

// ---------------- passB: per-bucket fine sort + degree/dinv (fused) ----------
__global__ __launch_bounds__(512) void passB_fine(const uint2* __restrict__ erec2,
                                                  const int* __restrict__ bstart,
                                                  uint* __restrict__ erecF,
                                                  int* __restrict__ estart, int* __restrict__ cnt,
                                                  float* __restrict__ dinv) {
    __shared__ int hist[256];
    __shared__ float wsum[256];
    __shared__ int off[256];
    __shared__ int cur[256];
    __shared__ int sd[256];
    int t = threadIdx.x, b = blockIdx.x;
    if (t < 256) { hist[t] = 0; wsum[t] = 0.f; }
    __syncthreads();
    int e0 = bstart[b], e1 = bstart[b + 1];
    for (int e = e0 + t; e < e1; e += 512) {
        uint2 r = erec2[e];
        int cl = (int)(r.y & 255u);
        atomicAdd(&hist[cl], 1);
        atomicAdd(&wsum[cl], __uint_as_float((r.x >> 17) << 16));
    }
    __syncthreads();
    int v = 0;
    if (t < 256) { v = hist[t]; sd[t] = v; }
    __syncthreads();
    for (int o = 1; o < 256; o <<= 1) {
        int x = (t >= o && t < 256) ? sd[t - o] : 0;
        __syncthreads();
        if (t < 256) sd[t] += x;
        __syncthreads();
    }
    if (t < 256) {
        off[t] = sd[t] - v;
        cur[t] = 0;
        int node = b * 256 + t;
        if (node < NN) {
            estart[node] = e0 + off[t];
            cnt[node] = v;
            dinv[node] = rsqrtf(1.0f + wsum[t]);   // 1 = self-loop weight
        }
    }
    __syncthreads();
    for (int e = e0 + t; e < e1; e += 512) {
        uint2 r = erec2[e];
        int cl = (int)(r.y & 255u);
        int p = atomicAdd(&cur[cl], 1);        // LDS atomic
        erecF[e0 + off[cl] + p] = r.x;         // dense per-node-sorted (hot 32KB window)
    }
}

// ---------------- xw = x @ [Wc_z | Wc_r | Wc_h]  (192B rows, dinv-folded) -----
// Feature j: zr-pair (z_j | r_j<<16) at byte 4j;  h_j at byte 128 + 2j.
// dinv[row] folded here. xw16 ALIASES erec2 (dead after passB; same stream).
__global__ __launch_bounds__(256) void gemm_xw_kernel(
        const float* __restrict__ x,
        const float* __restrict__ Wz, const float* __restrict__ Wr, const float* __restrict__ Wh,
        const float* __restrict__ dinv,
        ushort* __restrict__ xw16) {
    __shared__ float Bs[128 * 96];   // Bs[k*96 + c], k GLOBAL (0..127)
    __shared__ float AsT[8 * 128];   // AsT[kk*128 + row], kk local (0..7)
    int tid = threadIdx.x;
    int tx = tid & 31, ty = tid >> 5;
    int rowBase = blockIdx.x * 128;

    for (int e = tid; e < 4096; e += 256) { int k = e >> 5, c = e & 31; Bs[k * 96 + c]      = Wz[e]; }
    for (int e = tid; e < 4096; e += 256) { int k = e >> 5, c = e & 31; Bs[k * 96 + 32 + c] = Wr[e]; }
    for (int e = tid; e < 4096; e += 256) { int k = e >> 5, c = e & 31; Bs[k * 96 + 64 + c] = Wh[e]; }

    float acc0[16], acc1[16], acc2[16];
#pragma unroll
    for (int r = 0; r < 16; r++) { acc0[r] = 0.f; acc1[r] = 0.f; acc2[r] = 0.f; }

    int lr = tid >> 1;
    int lc = (tid & 1) * 4;
    for (int k0 = 0; k0 < 128; k0 += 8) {
        __syncthreads();
        int gr = rowBase + lr;
        vfloat4 a4 = (vfloat4)(0.f);
        if (gr < NN) a4 = __builtin_nontemporal_load((const vfloat4*)(x + (long long)gr * FIN + k0 + lc));
        AsT[(lc + 0) * 128 + lr] = a4.x;
        AsT[(lc + 1) * 128 + lr] = a4.y;
        AsT[(lc + 2) * 128 + lr] = a4.z;
        AsT[(lc + 3) * 128 + lr] = a4.w;
        __syncthreads();
#pragma unroll
        for (int kk = 0; kk < 8; kk++) {
            float b0 = Bs[(k0 + kk) * 96 + tx];
            float b1 = Bs[(k0 + kk) * 96 + 32 + tx];
            float b2 = Bs[(k0 + kk) * 96 + 64 + tx];
            const float4* ap = (const float4*)(AsT + kk * 128 + ty * 16);
            float4 a0 = ap[0], a1 = ap[1], a2 = ap[2], a3 = ap[3];
            float av[16] = {a0.x,a0.y,a0.z,a0.w, a1.x,a1.y,a1.z,a1.w,
                            a2.x,a2.y,a2.z,a2.w, a3.x,a3.y,a3.z,a3.w};
#pragma unroll
            for (int r = 0; r < 16; r++) {
                acc0[r] = fmaf(av[r], b0, acc0[r]);
                acc1[r] = fmaf(av[r], b1, acc1[r]);
                acc2[r] = fmaf(av[r], b2, acc2[r]);
            }
        }
    }
#pragma unroll
    for (int r = 0; r < 16; r++) {
        int gr = rowBase + ty * 16 + r;
        if (gr < NN) {
            float di = dinv[gr];
            ushort* o = xw16 + (long long)gr * 96;    // 192B row
            uint zr = (uint)f2bf(acc0[r] * di) | ((uint)f2bf(acc1[r] * di) << 16);
            *(uint*)(o + 2 * tx) = zr;                // 4B coalesced
            o[64 + tx] = f2bf(acc2[r] * di);          // 2B
        }
    }
}

// ---------------- fused gather-aggregate + GRU gates + head ----------------
// 32-lane group per node; 16 nodes / 512-thread block; NN = 6250*16 exactly.
// xw16 rows pre-scaled by dinv[row]:  agg = dinv[col]*(sum w_e*xw'[row_e] + xw'[col])
// 192B rows, two loads/edge (4B zr + 2B h).
// BARRIERS KEPT (register-pressure fences): removing them -> VGPR 80,
// occupancy 22% (rounds 3/4). Unroll-8 first tier (round 6: +3%).
// WT staging uses COALESCED global reads with (harmless) prologue LDS write
// conflicts: round 11 proved fixing the conflicts via strided global reads
// costs 10% — the conflicts are prologue-only and hidden by resident waves.
// Gate-phase WT reads (WzT[k*32+j]) are already bank-conflict-free.
__global__ __launch_bounds__(512) void agg_gate_kernel(
        const uint* __restrict__ erecF, const int* __restrict__ estart, const int* __restrict__ cnt,
        const ushort* __restrict__ xw16, const float* __restrict__ dinv,
        const float* __restrict__ hprev,
        const float* __restrict__ bcz, const float* __restrict__ bcr, const float* __restrict__ bch,
        const float* __restrict__ Wlz, const float* __restrict__ blz,
        const float* __restrict__ Wlr, const float* __restrict__ blr,
        const float* __restrict__ Wlh, const float* __restrict__ blh,
        const float* __restrict__ Whead, const float* __restrict__ bhead,
        float* __restrict__ y, float* __restrict__ hnew) {
    __shared__ float WzT[64 * 32], WrT[64 * 32], WhT[64 * 32];  // WT[k*32+j] = Wl[j*64+k]
    __shared__ float czs[16][32], crs[16][32], chs[16][32], hps[16][32], rhs[16][32];
    __shared__ uint rwsh[16][32];   // staged records per group
    int tid = threadIdx.x;
    for (int e2 = tid; e2 < 2048; e2 += 512) {
        int jj = e2 >> 6, k = e2 & 63;
        WzT[k * 32 + jj] = Wlz[e2];
        WrT[k * 32 + jj] = Wlr[e2];
        WhT[k * 32 + jj] = Wlh[e2];
    }
    int s = tid >> 5, j = tid & 31;
    int i = blockIdx.x * 16 + s;
    int beg = estart[i], c = cnt[i], end = beg + c;

    const char* xwb = (const char*)xw16;
    uint jo4 = 4u * (uint)j;            // byte offset of feature j's zr pair
    uint jo2 = 128u + 2u * (uint)j;     // byte offset of feature j's h

    float cz = 0.f, cr = 0.f, ch = 0.f;
    int e = beg + j;
    uint vcur = (e < end) ? __builtin_nontemporal_load(erecF + e) : 0u;   // batch 0
    __syncthreads();   // WT staging complete

#define REC(vv, aa, hh)                                                    \
    {                                                                      \
        float w_ = __uint_as_float(((vv) >> 17) << 16);                    \
        cz = fmaf(w_, __uint_as_float((aa) << 16), cz);                    \
        cr = fmaf(w_, __uint_as_float((aa) & 0xFFFF0000u), cr);            \
        ch = fmaf(w_, bf2f(hh), ch);                                       \
    }

    for (int base = beg; base < end; base += 32) {
        rwsh[s][j] = vcur;                      // in-order DS within wave: safe
        int en = base + 32 + j;
        uint vnext = (en < end) ? __builtin_nontemporal_load(erecF + en) : 0u;  // prefetch next batch
        int mm = end - base; if (mm > 32) mm = 32;
        int t = 0;
        for (; t + 8 <= mm; t += 8) {           // 16 loads in flight per group
            uint v0 = rwsh[s][t + 0], v1 = rwsh[s][t + 1], v2 = rwsh[s][t + 2], v3 = rwsh[s][t + 3];
            uint v4 = rwsh[s][t + 4], v5 = rwsh[s][t + 5], v6 = rwsh[s][t + 6], v7 = rwsh[s][t + 7];
            uint b0 = (v0 & 0x1FFFFu) * 192u, b1 = (v1 & 0x1FFFFu) * 192u;
            uint b2 = (v2 & 0x1FFFFu) * 192u, b3 = (v3 & 0x1FFFFu) * 192u;
            uint b4 = (v4 & 0x1FFFFu) * 192u, b5 = (v5 & 0x1FFFFu) * 192u;
            uint b6 = (v6 & 0x1FFFFu) * 192u, b7 = (v7 & 0x1FFFFu) * 192u;
            uint a0 = *(const uint*)(xwb + b0 + jo4);
            uint a1 = *(const uint*)(xwb + b1 + jo4);
            uint a2 = *(const uint*)(xwb + b2 + jo4);
            uint a3 = *(const uint*)(xwb + b3 + jo4);
            uint a4 = *(const uint*)(xwb + b4 + jo4);
            uint a5 = *(const uint*)(xwb + b5 + jo4);
            uint a6 = *(const uint*)(xwb + b6 + jo4);
            uint a7 = *(const uint*)(xwb + b7 + jo4);
            ushort h0 = *(const ushort*)(xwb + b0 + jo2);
            ushort h1 = *(const ushort*)(xwb + b1 + jo2);
            ushort h2 = *(const ushort*)(xwb + b2 + jo2);
            ushort h3 = *(const ushort*)(xwb + b3 + jo2);
            ushort h4 = *(const ushort*)(xwb + b4 + jo2);
            ushort h5 = *(const ushort*)(xwb + b5 + jo2);
            ushort h6 = *(const ushort*)(xwb + b6 + jo2);
            ushort h7 = *(const ushort*)(xwb + b7 + jo2);
            REC(v0, a0, h0) REC(v1, a1, h1) REC(v2, a2, h2) REC(v3, a3, h3)
            REC(v4, a4, h4) REC(v5, a5, h5) REC(v6, a6, h6) REC(v7, a7, h7)
        }
        for (; t + 4 <= mm; t += 4) {
            uint v0 = rwsh[s][t + 0], v1 = rwsh[s][t + 1], v2 = rwsh[s][t + 2], v3 = rwsh[s][t + 3];
            uint b0 = (v0 & 0x1FFFFu) * 192u, b1 = (v1 & 0x1FFFFu) * 192u;
            uint b2 = (v2 & 0x1FFFFu) * 192u, b3 = (v3 & 0x1FFFFu) * 192u;
            uint a0 = *(const uint*)(xwb + b0 + jo4);
            uint a1 = *(const uint*)(xwb + b1 + jo4);
            uint a2 = *(const uint*)(xwb + b2 + jo4);
            uint a3 = *(const uint*)(xwb + b3 + jo4);
            ushort h0 = *(const ushort*)(xwb + b0 + jo2);
            ushort h1 = *(const ushort*)(xwb + b1 + jo2);
            ushort h2 = *(const ushort*)(xwb + b2 + jo2);
            ushort h3 = *(const ushort*)(xwb + b3 + jo2);
            REC(v0, a0, h0) REC(v1, a1, h1) REC(v2, a2, h2) REC(v3, a3, h3)
        }
        for (; t < mm; t++) {
            uint v0 = rwsh[s][t];
            uint b0 = (v0 & 0x1FFFFu) * 192u;
            uint a0 = *(const uint*)(xwb + b0 + jo4);
            ushort h0 = *(const ushort*)(xwb + b0 + jo2);
            REC(v0, a0, h0)
        }
        vcur = vnext;
    }
#undef REC

    // self-loop + dinv[col] + bias:  c* = di*(sum + xw'[i]) + bc
    float di = dinv[i];
    uint bi = (uint)i * 192u;
    uint zri = *(const uint*)(xwb + bi + jo4);
    float hself = bf2f(*(const ushort*)(xwb + bi + jo2));
    czs[s][j] = fmaf(di, cz + __uint_as_float(zri << 16), bcz[j]);
    crs[s][j] = fmaf(di, cr + __uint_as_float(zri & 0xFFFF0000u), bcr[j]);
    chs[s][j] = fmaf(di, ch + hself, bch[j]);
    float hp = hprev[(long long)i * HD + j];
    hps[s][j] = hp;
    __syncthreads();   // register-pressure fence + cross-group visibility

    float az = blz[j], arv = blr[j];
#pragma unroll
    for (int k = 0; k < 32; k++) {
        az  = fmaf(WzT[k * 32 + j], czs[s][k], az);
        arv = fmaf(WrT[k * 32 + j], crs[s][k], arv);
    }
#pragma unroll
    for (int k = 0; k < 32; k++) {
        float v = hps[s][k];
        az  = fmaf(WzT[(k + 32) * 32 + j], v, az);
        arv = fmaf(WrT[(k + 32) * 32 + j], v, arv);
    }
    float Z = 1.f / (1.f + __expf(-az));
    float R = 1.f / (1.f + __expf(-arv));
    rhs[s][j] = hp * R;
    __syncthreads();   // register-pressure fence

    float ah = blh[j];
#pragma unroll
    for (int k = 0; k < 32; k++) ah = fmaf(WhT[k * 32 + j], chs[s][k], ah);
#pragma unroll
    for (int k = 0; k < 32; k++) ah = fmaf(WhT[(k + 32) * 32 + j], rhs[s][k], ah);
    float Ht = tanhf(ah);
    float hn = Z * hp + (1.f - Z) * Ht;
    float yv = fmaxf(hn, 0.f) * Whead[j];
#pragma unroll
    for (int m = 16; m; m >>= 1) yv += __shfl_xor(yv, m, 32);
    hnew[(long long)i * HD + j] = hn;
    if (j == 0) y[i] = yv + bhead[0];
}

extern "C" void kernel_launch(void* const* d_in, const int* in_sizes, int n_in,
                              void* d_out, int out_size, void* d_ws, size_t ws_size,
                              hipStream_t stream) {
    const float* x     = (const float*)d_in[0];
    const int*   ei    = (const int*)d_in[1];
    const float* wt    = (const float*)d_in[2];
    const float* hprev = (const float*)d_in[3];
    const float* Wcz = (const float*)d_in[4],  *bcz = (const float*)d_in[5];
    const float* Wlz = (const float*)d_in[6],  *blz = (const float*)d_in[7];
    const float* Wcr = (const float*)d_in[8],  *bcr = (const float*)d_in[9];
    const float* Wlr = (const float*)d_in[10], *blr = (const float*)d_in[11];
    const float* Wch = (const float*)d_in[12], *bch = (const float*)d_in[13];
    const float* Wlh = (const float*)d_in[14], *blh = (const float*)d_in[15];
    const float* Whead = (const float*)d_in[16], *bhead = (const float*)d_in[17];

    float* out_y = (float*)d_out;            // [N]
    float* out_h = (float*)d_out + NN;       // [N,32]

    float* ws = (float*)d_ws;
    float* dinv      = ws;                                   // NN f32
    int*   estart    = (int*)(ws + NN);                      // NN
    int*   cnt       = (int*)(ws + 2LL * NN);                // NN
    int*   bstart    = (int*)(ws + 3LL * NN);                // NBUK+1 (pad 512)
    int*   total     = (int*)(ws + 3LL * NN + 512);          // NBUK (pad 512)
    int*   blockhist = (int*)(ws + 3LL * NN + 1024);         // NBLK*NBUK=203711 (pad 204000)
    int*   off_local = (int*)(ws + 3LL * NN + 205024);       // 203711 (pad 204000)
    int*   flag      = (int*)(ws + 3LL * NN + 409024);       // 1 (pad 32)
    uint2*  erec2    = (uint2*)(ws + 3LL * NN + 409056);     // EE uint2 (8B-aligned)
    ushort* xw16     = (ushort*)erec2;                       // ALIAS: NN*192B (19.2MB) <= EE*8B (25.6MB)
    uint*   erecF    = (uint*)(ws + 3LL * NN + 409056 + 2LL * EE);  // EE uint

    passA_hist<<<NBLK, 256, 0, stream>>>(ei, blockhist, flag);
    scan_bucket<<<NBUK, 64, 0, stream>>>(blockhist, off_local, total);
    scan_total<<<1, 512, 0, stream>>>(total, bstart);
    sortC_kernel<<<NBLK, 512, 0, stream>>>(ei, wt, bstart, off_local, blockhist, erec2, flag);
    passB_fine<<<NBUK, 512, 0, stream>>>(erec2, bstart, erecF, estart, cnt, dinv);
    gemm_xw_kernel<<<(NN + 127) / 128, 256, 0, stream>>>(x, Wcz, Wcr, Wch, dinv, xw16);
    agg_gate_kernel<<<NN / 16, 512, 0, stream>>>(
        erecF, estart, cnt, xw16, dinv, hprev, bcz, bcr, bch,
        Wlz, blz, Wlr, blr, Wlh, blh, Whead, bhead, out_y, out_h);
}